// Round 1
// baseline (239.205 us; speedup 1.0000x reference)
//
#include <hip/hip_runtime.h>
#include <hip/hip_bf16.h>

#define HSZ 128
#define WSZ 128
#define HWSZ (HSZ*WSZ)      // 16384
#define NB 4

// ws layout (float offsets)
#define OFF_MB 0            // NPIX*4 floats: mask bias per (pixel, p)

typedef unsigned short u16;
typedef __attribute__((ext_vector_type(8))) short bf16x8;
typedef __attribute__((ext_vector_type(4))) float f32x4;

__device__ __forceinline__ float bf2f(u16 u) {
    return __uint_as_float(((unsigned int)u) << 16);
}
// packed fp32x2 -> bf16x2 (v_cvt_pk_bf16_f32 on gfx950), RNE
__device__ __forceinline__ unsigned int cvt_pk_bf16(float lo, float hi) {
    __hip_bfloat162 h = __float22bfloat162_rn(make_float2(lo, hi));
    return *(unsigned int*)&h;
}
__device__ __forceinline__ u16 f2bf_bits(float f) {
    unsigned int x = __float_as_uint(f);
    return (u16)((x + 0x7fffu + ((x >> 16) & 1u)) >> 16);
}
// A-frag slot swizzle: bijective on 0..63, spreads 16B slot starts over banks
__device__ __forceinline__ int sswz(int s) { return s ^ (s >> 3); }
// QKV tile index: conflict-free store banking, b128-aligned reads
__device__ __forceinline__ int qkv_idx(int t, int d) {
    return (t >> 2)*64 + ((((t & 3) + (t >> 2)) & 3) << 4) + d;
}
// lane's B-fragment: W[drow][k0..k0+7] as bf16 (B[k][n] with n=lane&15, k=quad*8+j)
__device__ __forceinline__ bf16x8 load_bfrag(const float* W, int drow, int k0) {
    float4 a = *(const float4*)(W + drow*64 + k0);
    float4 b = *(const float4*)(W + drow*64 + k0 + 4);
    unsigned int u[4];
    u[0] = cvt_pk_bf16(a.x, a.y); u[1] = cvt_pk_bf16(a.z, a.w);
    u[2] = cvt_pk_bf16(b.x, b.y); u[3] = cvt_pk_bf16(b.z, b.w);
    return *(bf16x8*)u;
}

// ---------------- Kernel 1: mask branch -> mb[pix][p] ----------------------
// mb = colmean(pw_w) . gelu(dwconv3x3(mask)+dw_b)   (mean(pw_b) cancels)
// 1024 thr = 4 channel-quarters x 256 pixel-slots; LDS reduce over quarters.
__global__ __launch_bounds__(1024) void mask_kernel(const float* __restrict__ mask,
                                                    const float* __restrict__ dww,
                                                    const float* __restrict__ dwb,
                                                    const float* __restrict__ pww,
                                                    float* __restrict__ ws) {
    __shared__ float red[4][256][4];   // 16 KB
    __shared__ float cmS[64];
    int tid = threadIdx.x;
    if (tid < 64) {                    // fold colmean(pw_w) into this kernel
        float s = 0.f;
        for (int co = 0; co < 64; ++co) s += pww[co*64 + tid];
        cmS[tid] = s * (1.0f/64.0f);
    }
    __syncthreads();
    int bid = blockIdx.x;              // 256 blocks: [bp(16)][hgroup(16)]
    int bp = bid >> 4;
    int hg = bid & 15;
    int cq = tid >> 8;                 // channel quarter 0..3
    int t = tid & 255;                 // pixel slot: 8 rows x 32 colgroups
    int h = hg*8 + (t >> 5);
    int w0 = (t & 31) << 2;
    const float* mb_ = mask + (size_t)bp*64*HWSZ;
    int hm = h > 0 ? h-1 : 0;
    int hp = h < 127 ? h+1 : 127;
    float vt = h > 0 ? 1.f : 0.f;
    float vb = h < 127 ? 1.f : 0.f;
    float vl = w0 > 0 ? 1.f : 0.f;
    float vr = w0 < 124 ? 1.f : 0.f;
    int wl = w0 > 0 ? w0-1 : 0;
    int wr = w0 < 124 ? w0+4 : 127;
    float acc0=0.f, acc1=0.f, acc2=0.f, acc3=0.f;
    for (int ci = 0; ci < 16; ++ci) {
        int c = cq*16 + ci;
        const float* rc = mb_ + c*HWSZ;
        const float* r0 = rc + hm*WSZ;
        const float* r1 = rc + h*WSZ;
        const float* r2 = rc + hp*WSZ;
        float4 m0 = *(const float4*)(r0 + w0);
        float4 m1 = *(const float4*)(r1 + w0);
        float4 m2 = *(const float4*)(r2 + w0);
        float L0 = r0[wl]*vl, L1 = r1[wl]*vl, L2 = r2[wl]*vl;
        float R0 = r0[wr]*vr, R1 = r1[wr]*vr, R2 = r2[wr]*vr;
        float w00 = dww[c*9+0]*vt, w01 = dww[c*9+1]*vt, w02 = dww[c*9+2]*vt;
        float w10 = dww[c*9+3],    w11 = dww[c*9+4],    w12 = dww[c*9+5];
        float w20 = dww[c*9+6]*vb, w21 = dww[c*9+7]*vb, w22 = dww[c*9+8]*vb;
        float bb = dwb[c];
        float s0 = bb + w00*L0   + w01*m0.x + w02*m0.y
                      + w10*L1   + w11*m1.x + w12*m1.y
                      + w20*L2   + w21*m2.x + w22*m2.y;
        float s1 = bb + w00*m0.x + w01*m0.y + w02*m0.z
                      + w10*m1.x + w11*m1.y + w12*m1.z
                      + w20*m2.x + w21*m2.y + w22*m2.z;
        float s2 = bb + w00*m0.y + w01*m0.z + w02*m0.w
                      + w10*m1.y + w11*m1.z + w12*m1.w
                      + w20*m2.y + w21*m2.z + w22*m2.w;
        float s3 = bb + w00*m0.z + w01*m0.w + w02*R0
                      + w10*m1.z + w11*m1.w + w12*R1
                      + w20*m2.z + w21*m2.w + w22*R2;
        float cmc = cmS[c];
        acc0 += cmc * (0.5f*s0*(1.f + erff(s0*0.70710678118654752f)));
        acc1 += cmc * (0.5f*s1*(1.f + erff(s1*0.70710678118654752f)));
        acc2 += cmc * (0.5f*s2*(1.f + erff(s2*0.70710678118654752f)));
        acc3 += cmc * (0.5f*s3*(1.f + erff(s3*0.70710678118654752f)));
    }
    red[cq][t][0] = acc0;
    red[cq][t][1] = acc1;
    red[cq][t][2] = acc2;
    red[cq][t][3] = acc3;
    __syncthreads();
    if (tid < 256) {
        int b = bp >> 2, p = bp & 3;
        size_t base = (size_t)b*HWSZ + h*WSZ + w0;
        #pragma unroll
        for (int e = 0; e < 4; ++e) {
            float v = red[0][tid][e] + red[1][tid][e] + red[2][tid][e] + red[3][tid][e];
            ws[OFF_MB + (base+e)*4 + p] = v;
        }
    }
}

// ---------------- Kernel 2: MFMA qkv + attention + MFMA proj ---------------
// 512 threads (8 waves) in the same 64 KB LDS: 2 blocks/CU -> 16 waves/CU
// (was 256 thr -> 8 waves/CU, 19.5% occupancy, latency-bound).
// Wave split: dq = wid&3 owns d-quarter, half = wid>>2 owns token half.
__global__ __launch_bounds__(512, 4) void attn_kernel(const float* __restrict__ x_in,
                                                      const float* __restrict__ wq,
                                                      const float* __restrict__ wk,
                                                      const float* __restrict__ wv,
                                                      const float* __restrict__ wp,
                                                      const float* __restrict__ bpj,
                                                      const float* __restrict__ rsc,
                                                      const float* __restrict__ ws,
                                                      float* __restrict__ out) {
    __shared__ u16 smem[32768];           // 64 KB
    u16* ldsA = smem;                     // 16 KB: x then y, swizzled A-frag order
    u16* ldsQ = smem + 8192;              // 16 KB: 32 tiles of qkv_idx layout
    u16* ldsK = smem + 16384;
    u16* ldsV = smem + 24576;
    float* outS = (float*)(smem + 8192);  // 32 KB fp32, overlays Q,K (phase 3)

    int t = threadIdx.x;
    int lane = t & 63;
    int wid = __builtin_amdgcn_readfirstlane(t >> 6);  // 0..7
    int dq = wid & 3;                     // d-quarter
    int half = wid >> 2;                  // token half (mt 0..3 / 4..7)
    int n15 = lane & 15;
    int quad = lane >> 4;
    int b = blockIdx.x >> 9;              // 2048 blocks = 4 b x 512
    int hw0 = (blockIdx.x & 511) << 5;

    // B-fragments (bf16) for this wave's d-quarter
    bf16x8 fq0 = load_bfrag(wq, dq*16 + n15, quad*8);
    bf16x8 fq1 = load_bfrag(wq, dq*16 + n15, 32 + quad*8);
    bf16x8 fk0 = load_bfrag(wk, dq*16 + n15, quad*8);
    bf16x8 fk1 = load_bfrag(wk, dq*16 + n15, 32 + quad*8);
    bf16x8 fv0 = load_bfrag(wv, dq*16 + n15, quad*8);
    bf16x8 fv1 = load_bfrag(wv, dq*16 + n15, 32 + quad*8);
    bf16x8 fp0 = load_bfrag(wp, dq*16 + n15, quad*8);
    bf16x8 fp1 = load_bfrag(wp, dq*16 + n15, 32 + quad*8);
    float bias = bpj[dq*16 + n15];

    // stage x -> ldsA: c-pair u32 writes, packed converts, swizzled slots
    unsigned int* ldsA32 = (unsigned int*)ldsA;
    for (int it = 0; it < 2; ++it) {
        int i = t + (it << 9);            // 0..1023: [rowpair(128)][l4(8)]
        int rp = i >> 3, l4 = i & 7;
        int p = rp >> 5, cp = rp & 31;
        int c0 = cp*2;
        const float* r0 = x_in + (size_t)(b*256 + p*64 + c0)*HWSZ + hw0 + l4*4;
        float4 v0 = *(const float4*)r0;
        float4 v1 = *(const float4*)(r0 + HWSZ);
        int kt = c0 >> 5, qd = (c0 >> 3) & 3, j2 = (c0 & 7) >> 1;
        float a0[4] = {v0.x, v0.y, v0.z, v0.w};
        float a1[4] = {v1.x, v1.y, v1.z, v1.w};
        #pragma unroll
        for (int e = 0; e < 4; ++e) {
            int tau = (p << 5) + (l4 << 2) + e;
            int slot = (tau & 15) | (qd << 4);
            ldsA32[((tau >> 4)*2 + kt)*256 + sswz(slot)*4 + j2] = cvt_pk_bf16(a0[e], a1[e]);
        }
    }
    __syncthreads();

    // ---- phase 1: Q,K,V GEMMs (each wave: 4 token-tiles of its half) ----
    int sl8 = sswz(lane)*8;
    for (int m = 0; m < 4; ++m) {
        int mt = (half << 2) + m;
        bf16x8 a0 = *(const bf16x8*)(ldsA + mt*1024 + sl8);
        bf16x8 a1 = *(const bf16x8*)(ldsA + mt*1024 + 512 + sl8);
        f32x4 aq = {0.f,0.f,0.f,0.f};
        f32x4 ak = {0.f,0.f,0.f,0.f};
        f32x4 av = {0.f,0.f,0.f,0.f};
        aq = __builtin_amdgcn_mfma_f32_16x16x32_bf16(a0, fq0, aq, 0, 0, 0);
        aq = __builtin_amdgcn_mfma_f32_16x16x32_bf16(a1, fq1, aq, 0, 0, 0);
        ak = __builtin_amdgcn_mfma_f32_16x16x32_bf16(a0, fk0, ak, 0, 0, 0);
        ak = __builtin_amdgcn_mfma_f32_16x16x32_bf16(a1, fk1, ak, 0, 0, 0);
        av = __builtin_amdgcn_mfma_f32_16x16x32_bf16(a0, fv0, av, 0, 0, 0);
        av = __builtin_amdgcn_mfma_f32_16x16x32_bf16(a1, fv1, av, 0, 0, 0);
        int tb = (mt*4 + dq)*256;         // C: col(n15)=d, row(quad*4+r)=token
        #pragma unroll
        for (int r = 0; r < 4; ++r) {
            int idx = tb + quad*64 + ((((r + quad) & 3)) << 4) + n15;
            ldsQ[idx] = f2bf_bits(aq[r]);
            ldsK[idx] = f2bf_bits(ak[r]);
            ldsV[idx] = f2bf_bits(av[r]);
        }
    }
    __syncthreads();

    // ---- phase 2: attention core (1 thread = (pix, head, q-pair)) ----
    {
        int pix = t & 31;
        int hd = (t >> 5) & 7;
        int ph = t >> 8;                  // q rows {2ph, 2ph+1}
        float qv[2][8], kv[4][8], vv[4][8];
        #pragma unroll
        for (int p = 0; p < 4; ++p) {
            int tau = (p << 5) + pix;
            int base = ((tau >> 4)*4 + (hd >> 1))*256 + qkv_idx(tau & 15, (hd & 1)*8);
            bf16x8 k8 = *(const bf16x8*)(ldsK + base);
            bf16x8 v8 = *(const bf16x8*)(ldsV + base);
            #pragma unroll
            for (int j = 0; j < 8; ++j) {
                kv[p][j] = bf2f((u16)k8[j]);
                vv[p][j] = bf2f((u16)v8[j]);
            }
        }
        #pragma unroll
        for (int pq = 0; pq < 2; ++pq) {
            int tau = (((ph << 1) + pq) << 5) + pix;
            int base = ((tau >> 4)*4 + (hd >> 1))*256 + qkv_idx(tau & 15, (hd & 1)*8);
            bf16x8 q8 = *(const bf16x8*)(ldsQ + base);
            #pragma unroll
            for (int j = 0; j < 8; ++j) qv[pq][j] = bf2f((u16)q8[j]);
        }
        #pragma unroll
        for (int p = 0; p < 4; ++p) {
            float sk = 0.f;
            #pragma unroll
            for (int j = 0; j < 8; ++j) sk += kv[p][j]*kv[p][j];
            float ik = 1.0f / fmaxf(sqrtf(sk), 1e-12f);
            #pragma unroll
            for (int j = 0; j < 8; ++j) kv[p][j] *= ik;
        }
        #pragma unroll
        for (int pq = 0; pq < 2; ++pq) {
            float sq = 0.f;
            #pragma unroll
            for (int j = 0; j < 8; ++j) sq += qv[pq][j]*qv[pq][j];
            float iq = 1.0f / fmaxf(sqrtf(sq), 1e-12f);
            #pragma unroll
            for (int j = 0; j < 8; ++j) qv[pq][j] *= iq;
        }
        float4 mb4 = *(const float4*)(ws + OFF_MB + ((size_t)b*HWSZ + hw0 + pix)*4);
        float mba[4] = {mb4.x, mb4.y, mb4.z, mb4.w};
        float rs = rsc[hd];
        unsigned int* ldsA32w = (unsigned int*)ldsA;
        #pragma unroll
        for (int pq = 0; pq < 2; ++pq) {
            int p = (ph << 1) + pq;
            float at[4];
            #pragma unroll
            for (int r = 0; r < 4; ++r) {
                float d = 0.f;
                #pragma unroll
                for (int j = 0; j < 8; ++j) d += qv[pq][j]*kv[r][j];
                at[r] = d*rs + mba[r];      // -mb[p] cancels in softmax
            }
            float m = fmaxf(fmaxf(at[0], at[1]), fmaxf(at[2], at[3]));
            float e0 = __expf(at[0]-m), e1 = __expf(at[1]-m);
            float e2 = __expf(at[2]-m), e3 = __expf(at[3]-m);
            float inv = 1.0f / (e0+e1+e2+e3);
            at[0]=e0*inv; at[1]=e1*inv; at[2]=e2*inv; at[3]=e3*inv;
            float y[8];
            #pragma unroll
            for (int j = 0; j < 8; ++j) {
                y[j] = at[0]*vv[0][j] + at[1]*vv[1][j]
                     + at[2]*vv[2][j] + at[3]*vv[3][j];
            }
            int tau = (p << 5) + pix;       // y -> ldsA A-frag: d = hd*8+j
            int slot = (tau & 15) | ((hd & 3) << 4);
            unsigned int pk[4];
            pk[0] = cvt_pk_bf16(y[0], y[1]); pk[1] = cvt_pk_bf16(y[2], y[3]);
            pk[2] = cvt_pk_bf16(y[4], y[5]); pk[3] = cvt_pk_bf16(y[6], y[7]);
            *(uint4*)(ldsA32w + ((tau >> 4)*2 + (hd >> 2))*256 + sswz(slot)*4) = *(uint4*)pk;
        }
    }
    __syncthreads();

    // ---- phase 3: proj GEMM + bias, transpose via swizzled LDS ----
    for (int m = 0; m < 4; ++m) {
        int mt = (half << 2) + m;
        bf16x8 a0 = *(const bf16x8*)(ldsA + mt*1024 + sl8);
        bf16x8 a1 = *(const bf16x8*)(ldsA + mt*1024 + 512 + sl8);
        f32x4 ao = {0.f,0.f,0.f,0.f};
        ao = __builtin_amdgcn_mfma_f32_16x16x32_bf16(a0, fp0, ao, 0, 0, 0);
        ao = __builtin_amdgcn_mfma_f32_16x16x32_bf16(a1, fp1, ao, 0, 0, 0);
        #pragma unroll
        for (int r = 0; r < 4; ++r) {
            int tau = mt*16 + quad*4 + r;
            int d = dq*16 + n15;
            outS[tau*64 + (d ^ (tau & 31))] = ao[r] + bias;
        }
    }
    __syncthreads();
    #pragma unroll
    for (int g = 0; g < 4; ++g) {
        int flat = (g << 9) + t;          // 0..2047, 4 px per thread
        int px = (flat & 7) << 2;
        int pd = flat >> 3;               // [p(4)][d(64)]
        int d = pd & 63;
        int p = pd >> 6;
        int tb0 = (p << 5) + px;
        float4 o;
        o.x = outS[(tb0+0)*64 + (d ^ ((tb0+0) & 31))];
        o.y = outS[(tb0+1)*64 + (d ^ ((tb0+1) & 31))];
        o.z = outS[(tb0+2)*64 + (d ^ ((tb0+2) & 31))];
        o.w = outS[(tb0+3)*64 + (d ^ ((tb0+3) & 31))];
        *(float4*)(out + (size_t)((b*4 + p)*64 + d)*HWSZ + hw0 + px) = o;
    }
}

extern "C" void kernel_launch(void* const* d_in, const int* in_sizes, int n_in,
                              void* d_out, int out_size, void* d_ws, size_t ws_size,
                              hipStream_t stream) {
    const float* x_in  = (const float*)d_in[0];
    const float* mask  = (const float*)d_in[1];
    const float* wq    = (const float*)d_in[2];
    const float* wk    = (const float*)d_in[3];
    const float* wv    = (const float*)d_in[4];
    const float* wproj = (const float*)d_in[5];
    const float* bproj = (const float*)d_in[6];
    const float* resc  = (const float*)d_in[7];
    const float* dww   = (const float*)d_in[8];
    const float* dwb   = (const float*)d_in[9];
    const float* pww   = (const float*)d_in[10];
    float* ws = (float*)d_ws;
    float* outp = (float*)d_out;

    hipLaunchKernelGGL(mask_kernel, dim3(256), dim3(1024), 0, stream,
                       mask, dww, dwb, pww, ws);
    hipLaunchKernelGGL(attn_kernel, dim3(2048), dim3(512), 0, stream,
                       x_in, wq, wk, wv, wproj, bproj, resc, ws, outp);
}